// Round 9
// baseline (2293.454 us; speedup 1.0000x reference)
//
#include <hip/hip_runtime.h>

// ---------------------------------------------------------------------------
// SparsePoolingLayer: u0 = conv5x5_valid(x, W_ff); iterate
//   u <- 0.5*u + 0.5*(u0 - W_rec @ a); a = relu(u - thr)
// until ||u_new - u||/||u_new|| < 1e-3 (device-checked), max 41 iterations.
//
// R9: K=4 iteration fusion. The update is pointwise in n, so a block
// (64 n x all 256 oc) runs 4 consecutive iterations with u held in its
// sv registers: HBM per launch = u r + 4x u0 r + u w = 354 MB for 4 iters
// (u0 re-reads mostly L3-hits) vs 4x177 MB unfused. Launches 41 -> 11.
// Convergence checked at launch granularity (norms written for each
// launch's last virtual iteration only); <=3-iteration overshoot shifts
// output by ~2e-3 relative -- inside the error budget. u fp16 [n][oc]
// (R7/R8: fp16 noise floor 1.4e-4 << 1e-3 threshold; bf16's 1.1e-3 broke
// the check in R5). a_lds cells are written/read by the same thread in
// phases 1/4 -> the fused loop keeps just 3 barriers per iteration.
// ---------------------------------------------------------------------------

typedef __attribute__((ext_vector_type(8))) short short8;
typedef __attribute__((ext_vector_type(4))) float f32x4;

#define NTOT 115200   // 32*60*60
#define CHW  262144   // 64*64*64
#define HW2  4096     // 64*64
#define LDA  264      // a_lds row stride in shorts (528 B)

__device__ __forceinline__ unsigned short f2bf(float f) {
  unsigned int u = __float_as_uint(f);
  unsigned int r = u + 0x7FFFu + ((u >> 16) & 1u);
  return (unsigned short)(r >> 16);
}
__device__ __forceinline__ float bf2f(unsigned short h) {
  return __uint_as_float(((unsigned int)h) << 16);
}
__device__ __forceinline__ unsigned short f2h(float f) {
  _Float16 x = (_Float16)f;
  unsigned short r;
  __builtin_memcpy(&r, &x, 2);
  return r;
}
__device__ __forceinline__ float h2f(unsigned short h) {
  _Float16 x;
  __builtin_memcpy(&x, &h, 2);
  return (float)x;
}

// ---------------------------------------------------------------------------
// Weight prep:
//  wff[o][(ky*5+kx)*64+ci] bf16  (conv A operand rows)
//  wrec_sw: per-lane MFMA fragment order: for 8-wide ic-chunk cc (0..31),
//  oc row o: wrec_sw[((cc*256)+o)*8 + j] = W_rec[o][cc*8+j]
__global__ void cast_weights(const float* __restrict__ wff_f,
                             const float* __restrict__ wrec_f,
                             unsigned short* __restrict__ wff,
                             unsigned short* __restrict__ wrec_sw) {
  int tid = blockIdx.x * 256 + threadIdx.x;
  if (tid < 409600) {
    int o = tid / 1600, k = tid % 1600;
    int kk = k >> 6, ci = k & 63;            // k = kk*64 + ci
    wff[tid] = f2bf(wff_f[o * 1600 + ci * 25 + kk]);
  } else if (tid < 409600 + 65536) {
    int i = tid - 409600;
    int o = i >> 8, ic = i & 255;
    wrec_sw[(((ic >> 3) << 8) + o) * 8 + (ic & 7)] = f2bf(wrec_f[i]);
  }
}

// ---------------------------------------------------------------------------
// x NCHW fp32 -> NHWC bf16: xt[(b*4096 + y*64 + x)*64 + ci].
__global__ __launch_bounds__(256) void transpose_x(
    const float* __restrict__ x, unsigned short* __restrict__ xt) {
  int g = blockIdx.x * 256 + threadIdx.x;          // 131072 = 32*4096
  const float* src = x + (long)(g >> 12) * CHW + (g & 4095);
  unsigned short* dst = xt + (long)g * 64;
#pragma unroll
  for (int oct = 0; oct < 8; ++oct) {
    alignas(16) unsigned short tmp[8];
#pragma unroll
    for (int d = 0; d < 8; ++d)
      tmp[d] = f2bf(src[(oct * 8 + d) * HW2]);
    *(int4*)(dst + oct * 8) = *(const int4*)tmp;
  }
}

// ---------------------------------------------------------------------------
// Conv as implicit GEMM, D[oc][n] (A = wff, B = x). Block 128oc x 128n,
// BK=32, grid (900, 2). Writes u0 bf16 [n][oc] as uint2 (4 oc per lane).
__global__ __launch_bounds__(256) void conv_kernel(
    const unsigned short* __restrict__ xt,
    const unsigned short* __restrict__ wff,
    unsigned short* __restrict__ u0_nc) {
  __shared__ short As[128 * 40];   // x-tile  [n][k]  pad 32->40
  __shared__ short Bs[128 * 40];   // wff     [oc][k]
  const int t = threadIdx.x;
  const int n0 = blockIdx.x * 128;
  const int oc0 = blockIdx.y * 128;
  const int lane = t & 63, w = t >> 6;
  const int q = lane >> 4, r = lane & 15;
  const int woc = w >> 1, wn = w & 1;      // oc-half, n-half
  const int qt = t & 3, mrow = t >> 2;     // staging: row mrow(+64), 16B qt

  int xbase[2];
#pragma unroll
  for (int p = 0; p < 2; ++p) {
    int n = n0 + p * 64 + mrow;
    int bb = n / 3600, rem = n - bb * 3600;
    int yy = rem / 60, xx = rem - yy * 60;
    xbase[p] = (bb * 4096 + yy * 64 + xx) * 64 + qt * 8;
  }

  f32x4 acc[4][4];
#pragma unroll
  for (int i = 0; i < 4; i++)
#pragma unroll
    for (int j = 0; j < 4; j++) acc[i][j] = (f32x4){0.f, 0.f, 0.f, 0.f};

  for (int c = 0; c < 50; ++c) {
    const int k0 = c * 32;
    const int kk = c >> 1;                 // ky*5+kx, uniform per chunk
    const int ky = kk / 5, kx = kk - ky * 5;
    const int choff = (ky * 64 + kx) * 64 + (c & 1) * 32;  // scalar-uniform

    __syncthreads();
#pragma unroll
    for (int p = 0; p < 2; ++p) {          // wff: 128 oc-rows x 32 k
      int m = p * 64 + mrow;
      *(int4*)(&Bs[m * 40 + qt * 8]) =
          *(const int4*)(wff + (oc0 + m) * 1600 + k0 + qt * 8);
    }
#pragma unroll
    for (int p = 0; p < 2; ++p) {          // x-tile: contiguous bf16 (NHWC)
      int m = p * 64 + mrow;
      *(int4*)(&As[m * 40 + qt * 8]) = *(const int4*)(xt + xbase[p] + choff);
    }
    __syncthreads();

    short8 xf[4], wf[4];
#pragma unroll
    for (int j = 0; j < 4; j++)
      xf[j] = *(const short8*)(&As[(wn * 64 + j * 16 + r) * 40 + q * 8]);
#pragma unroll
    for (int i = 0; i < 4; i++)
      wf[i] = *(const short8*)(&Bs[(woc * 64 + i * 16 + r) * 40 + q * 8]);
#pragma unroll
    for (int i = 0; i < 4; i++)
#pragma unroll
      for (int j = 0; j < 4; j++)
        acc[i][j] = __builtin_amdgcn_mfma_f32_16x16x32_bf16(wf[i], xf[j],
                                                            acc[i][j], 0, 0, 0);
  }

  // epilogue: lane holds 4 consecutive oc (d) at fixed n -> uint2 stores
#pragma unroll
  for (int j = 0; j < 4; j++) {
    const int n = n0 + wn * 64 + j * 16 + r;
#pragma unroll
    for (int i = 0; i < 4; i++) {
      const int oc = oc0 + woc * 64 + i * 16 + q * 4;
      alignas(8) unsigned short up[4];
#pragma unroll
      for (int d = 0; d < 4; ++d) up[d] = f2bf(acc[i][j][d]);
      *(uint2*)(&u0_nc[n * 256 + oc]) = *(const uint2*)up;
    }
  }
}

// ---------------------------------------------------------------------------
// Fused multi-iteration kernel. Block = 64 n x 256 oc, grid 1800. Runs
// virtual iterations it0 .. it0+nits-1 with u in registers (sv) throughout:
//   per s: a=relu(sv-thr) -> a_lds | barrier | GEMM (wrec frags from L2) |
//   barrier | rec -> a_lds (fp16, C-layout) | barrier | update sv
//   (u0 re-read from global, L3-resident; norms only for the last s).
// After the loop sv -> u. Convergence checked at launch entry against the
// previous launch's last-iteration norms.
template <int FIRST>
__global__ __launch_bounds__(256, 3) void iter_kernel(
    const unsigned short* __restrict__ wrec_sw,
    const unsigned short* __restrict__ u0, const float* __restrict__ thr,
    unsigned short* __restrict__ u, float* __restrict__ norms,
    int* __restrict__ flag, int it0, int nits) {
  __shared__ short a_lds[64 * LDA];
  __shared__ float red[8];

  const int t = threadIdx.x;
  if (!FIRST) {
    if (*(volatile int*)flag) return;                      // converged earlier
    float d2p = norms[2 * (it0 - 1)], n2p = norms[2 * (it0 - 1) + 1];
    if (d2p < 1e-6f * n2p) {                               // fro ratio < 1e-3
      if (t == 0) *flag = 1;
      return;
    }
  }

  const int n0 = blockIdx.x * 64;
  const int ch = t & 31;                   // 8-oc chunk
  const int row0 = t >> 5;                 // rows row0 + 8p
  const int occh = ch * 8;

  float4 th0 = *(const float4*)(thr + occh);
  float4 th1 = *(const float4*)(thr + occh + 4);
  float thc[8] = {th0.x, th0.y, th0.z, th0.w, th1.x, th1.y, th1.z, th1.w};

  const int lane = t & 63, w = t >> 6;
  const int q = lane >> 4, r = lane & 15;

  // ---- initial u state -> sv (packed fp16) ----
  int4 sv[8];
#pragma unroll
  for (int p = 0; p < 8; ++p) {
    const int base = (n0 + row0 + p * 8) * 256 + occh;
    if (FIRST) {
      int4 raw = *(const int4*)(u0 + base);        // 8 bf16
      const unsigned short* rs = (const unsigned short*)&raw;
      alignas(16) unsigned short hp[8];
#pragma unroll
      for (int d = 0; d < 8; ++d) hp[d] = f2h(bf2f(rs[d]));  // exact
      sv[p] = *(const int4*)hp;
    } else {
      sv[p] = *(const int4*)(u + base);            // 8 fp16
    }
  }

  float d2 = 0.f, n2 = 0.f;
  for (int s = 0; s < nits; ++s) {
    const bool first_it = (FIRST && s == 0);
    const bool last_it = (s == nits - 1);

    // ---- phase 1: a = relu(sv - thr) -> a_lds ----
#pragma unroll
    for (int p = 0; p < 8; ++p) {
      const unsigned short* hs = (const unsigned short*)&sv[p];
      alignas(16) unsigned short ap[8];
#pragma unroll
      for (int d = 0; d < 8; ++d) {
        float a = h2f(hs[d]) - thc[d];
        ap[d] = f2bf(a > 0.f ? a : 0.f);
      }
      *(int4*)(&a_lds[(row0 + p * 8) * LDA + occh]) = *(const int4*)ap;
    }
    __syncthreads();

    // ---- phase 2: GEMM ----
    f32x4 acc[4][4];
#pragma unroll
    for (int i = 0; i < 4; i++)
#pragma unroll
      for (int j = 0; j < 4; j++) acc[i][j] = (f32x4){0.f, 0.f, 0.f, 0.f};

#pragma unroll
    for (int c = 0; c < 8; ++c) {
      short8 afr[4], bfr[4];
#pragma unroll
      for (int i = 0; i < 4; i++)
        afr[i] = *(const short8*)(wrec_sw +
                 (((c * 4 + q) << 8) + w * 64 + i * 16 + r) * 8);
#pragma unroll
      for (int j = 0; j < 4; j++)
        bfr[j] = *(const short8*)(&a_lds[(j * 16 + r) * LDA + c * 32 + q * 8]);
#pragma unroll
      for (int i = 0; i < 4; i++)
#pragma unroll
        for (int j = 0; j < 4; j++)
          acc[i][j] = __builtin_amdgcn_mfma_f32_16x16x32_bf16(
              afr[i], bfr[j], acc[i][j], 0, 0, 0);
    }

    // ---- phase 3: rec (C-layout) -> a_lds row-major, fp16 ----
    __syncthreads();                       // all a_lds GEMM reads done
#pragma unroll
    for (int j = 0; j < 4; j++) {
      const int nr = j * 16 + r;
#pragma unroll
      for (int i = 0; i < 4; i++) {
        const int oc = w * 64 + i * 16 + q * 4;
        alignas(8) unsigned short rp[4];
#pragma unroll
        for (int d = 0; d < 4; ++d) rp[d] = f2h(acc[i][j][d]);
        *(uint2*)(&a_lds[nr * LDA + oc]) = *(const uint2*)rp;
      }
    }
    __syncthreads();

    // ---- phase 4: sv update (+ norms on the last virtual iteration) ----
#pragma unroll
    for (int p = 0; p < 8; ++p) {
      const int base = (n0 + row0 + p * 8) * 256 + occh;
      int4 rr = *(const int4*)(&a_lds[(row0 + p * 8) * LDA + occh]);
      const unsigned short* rs = (const unsigned short*)&rr;
      const unsigned short* hs = (const unsigned short*)&sv[p];
      float u0v[8];
      if (first_it) {
#pragma unroll
        for (int d = 0; d < 8; ++d) u0v[d] = h2f(hs[d]);
      } else {
        int4 u0p = *(const int4*)(u0 + base);
        const unsigned short* us = (const unsigned short*)&u0p;
#pragma unroll
        for (int d = 0; d < 8; ++d) u0v[d] = bf2f(us[d]);
      }
      alignas(16) unsigned short up[8];
#pragma unroll
      for (int d = 0; d < 8; ++d) {
        float uo = first_it ? 0.f : h2f(hs[d]);
        float un = 0.5f * uo + 0.5f * (u0v[d] - h2f(rs[d]));
        if (last_it) {
          float df = un - uo;
          d2 += df * df;
          n2 += un * un;
        }
        up[d] = f2h(un);
      }
      sv[p] = *(const int4*)up;
    }
    // no barrier: a_lds cells touched in phases 1/4 belong to this thread;
    // the next GEMM's reads are fenced by the phase-1 barrier.
  }

  // ---- write back u ----
#pragma unroll
  for (int p = 0; p < 8; ++p) {
    const int base = (n0 + row0 + p * 8) * 256 + occh;
    *(int4*)(u + base) = sv[p];
  }

  // ---- norms for virtual iteration it0+nits-1 ----
#pragma unroll
  for (int off = 32; off; off >>= 1) {
    d2 += __shfl_down(d2, off, 64);
    n2 += __shfl_down(n2, off, 64);
  }
  if (lane == 0) { red[w] = d2; red[4 + w] = n2; }
  __syncthreads();
  if (t == 0) {
    const int slot = it0 + nits - 1;
    atomicAdd(&norms[2 * slot], red[0] + red[1] + red[2] + red[3]);
    atomicAdd(&norms[2 * slot + 1], red[4] + red[5] + red[6] + red[7]);
  }
}

// ---------------------------------------------------------------------------
// Final: out(NCHW fp32) = relu(u - thr), u fp16 [n][oc]. Block = 64 n; wave
// w handles oc [64w, 64w+64) = 8 int4 groups of 8 fp16.
__global__ __launch_bounds__(256) void final_out(
    const unsigned short* __restrict__ u, const float* __restrict__ thr,
    float* __restrict__ out) {
  const int t = threadIdx.x, lane = t & 63, w = t >> 6;
  const int n = blockIdx.x * 64 + lane;
  const int b = n / 3600, s = n - b * 3600;
  float* ob = out + (long)b * 921600 + s;
  const unsigned short* ub = u + (long)n * 256 + w * 64;
#pragma unroll
  for (int g = 0; g < 8; ++g) {            // 8 groups x 8 fp16 = 64 oc
    int4 raw = *(const int4*)(ub + g * 8);
    const unsigned short* rs = (const unsigned short*)&raw;
#pragma unroll
    for (int d = 0; d < 8; ++d) {
      int oc = w * 64 + g * 8 + d;
      float v = h2f(rs[d]) - thr[oc];
      ob[oc * 3600] = v > 0.f ? v : 0.f;
    }
  }
}

// ---------------------------------------------------------------------------
extern "C" void kernel_launch(void* const* d_in, const int* in_sizes, int n_in,
                              void* d_out, int out_size, void* d_ws,
                              size_t ws_size, hipStream_t stream) {
  const float* x      = (const float*)d_in[0];
  const float* wff_f  = (const float*)d_in[1];
  const float* wrec_f = (const float*)d_in[2];
  const float* thr    = (const float*)d_in[3];
  float* out = (float*)d_out;

  char* ws = (char*)d_ws;
  int* flag = (int*)ws;                                      // [0,4)
  float* norms = (float*)(ws + 64);                          // [64, 400)
  unsigned short* wff     = (unsigned short*)(ws + 1024);      // 819200 B
  unsigned short* wrec_sw = (unsigned short*)(ws + 851968);    // 131072 B
  // xt (16.8 MB) aliases the head of u (59 MB): xt dies after conv, u is
  // first written by iter_kernel<1>.
  unsigned short* xt = (unsigned short*)(ws + 983040);
  unsigned short* u  = (unsigned short*)(ws + 983040);         // 58982400 B
  unsigned short* u0 = (unsigned short*)(ws + 59965440);       // 58982400 B
  // total ws: ~119 MB

  hipMemsetAsync(d_ws, 0, 1024, stream);  // flag + norm slots
  cast_weights<<<1856, 256, 0, stream>>>(wff_f, wrec_f, wff, wrec_sw);
  transpose_x<<<512, 256, 0, stream>>>(x, xt);
  conv_kernel<<<dim3(900, 2), 256, 0, stream>>>(xt, wff, u0);
  // virtual iterations 1..41 in fused launches of 4 (last launch = 1)
  iter_kernel<1><<<1800, 256, 0, stream>>>(wrec_sw, u0, thr, u, norms, flag,
                                           1, 4);
  for (int it0 = 5; it0 <= 37; it0 += 4)
    iter_kernel<0><<<1800, 256, 0, stream>>>(wrec_sw, u0, thr, u, norms, flag,
                                             it0, 4);
  iter_kernel<0><<<1800, 256, 0, stream>>>(wrec_sw, u0, thr, u, norms, flag,
                                           41, 1);
  final_out<<<1800, 256, 0, stream>>>(u, thr, out);
}